// Round 12
// baseline (306.225 us; speedup 1.0000x reference)
//
#include <hip/hip_runtime.h>
#include <stdint.h>
#include <stddef.h>

// ---------------------------------------------------------------------------
// VQ-VAE quantizer, MI355X.  dist(n,k) = ||x||^2 + ||w_k||^2 - 2 x.w_k.
// f16 GEMM (KD=128), fragment-linear A/B.
// Refine: per-row threshold T = d1~ + 2E; exact compares via u64 atomicMin.
// R16: fragments staged via global_load_lds (2x16 KB dbuf).  R9/R20:
// gemm flat ~55-61 us across 4 structural variants -> VALU floor; frozen.
// R22: half-group (64-code) refine granularity; full-codebook rescan gone.
// R23 (this round): CSR machinery ELIMINATED.  EMA sums via direct f32
// atomic scatter-add (2M fire-and-forget, avg 2 rows/code -> ~no
// contention; summation order was already nondeterministic via cursor
// atomics; 0.01*mean order-noise ~1e-9 << tol).  scan_offsets +
// fill_rowlist nodes deleted (8 -> 6); qsum EMA reads sums/cnt as a pure
// contiguous stream.  sums aliases pd2h region (classify = last pd2h
// reader; refine zeroes it; resolve scatters after).  resolve widened to
// 4 lanes/row (same-wave lockstep for the ids read->write).
// ---------------------------------------------------------------------------

#define N_ROWS   16384      // B*H*W = 16*32*32
#define K_CODES  8192
#define C_DIM    128
#define ITEMS_CAP 32768u

typedef _Float16 f16x8 __attribute__((ext_vector_type(8)));
typedef float    f32x4 __attribute__((ext_vector_type(4)));

// ---------------- fused prep: blocks [0,256) pack x (+fp32 xT), [256,384) w
__global__ __launch_bounds__(256) void prep(const float* __restrict__ enc,
                                            const float* __restrict__ w,
                                            _Float16* __restrict__ Ap,
                                            _Float16* __restrict__ Bp,
                                            float* __restrict__ xT,
                                            float* __restrict__ xnorm,
                                            float* __restrict__ wnorm,
                                            float* __restrict__ wnmax128) {
  __shared__ float t[128][65];
  const int tid = threadIdx.x;
  if (blockIdx.x < 256) {                        // ---- x path
    const int b = blockIdx.x >> 4;
    const int hw0 = (blockIdx.x & 15) << 6;
    #pragma unroll
    for (int i = 0; i < 32; ++i) {
      int idx = i * 256 + tid;
      int c = idx >> 6, hwl = idx & 63;
      t[c][hwl] = enc[((size_t)(b * 128 + c) << 10) + hw0 + hwl];
    }
    __syncthreads();
    const int r = tid >> 2, sub = tid & 3;       // row-in-block, k-chunk
    const int n = (b << 10) + hw0 + r;
    const int R = n >> 4, m = n & 15;
    float s = 0.f;
    #pragma unroll
    for (int q = 0; q < 4; ++q) {
      f16x8 hv;
      float vv[8];
      #pragma unroll
      for (int e = 0; e < 8; ++e) {
        float v = t[sub * 32 + q * 8 + e][r];
        vv[e] = v;
        s += v * v;
        hv[e] = (_Float16)v;
      }
      *(f16x8*)(Ap + ((size_t)(R * 4 + sub) * 64 + (m + 16 * q)) * 8) = hv;
      *(float4*)(xT + (size_t)n * 128 + sub * 32 + q * 8) =
          (float4){vv[0], vv[1], vv[2], vv[3]};
      *(float4*)(xT + (size_t)n * 128 + sub * 32 + q * 8 + 4) =
          (float4){vv[4], vv[5], vv[6], vv[7]};
    }
    s += __shfl_xor(s, 1);
    s += __shfl_xor(s, 2);
    if (sub == 0) xnorm[n] = s;
  } else {                                       // ---- w path
    __shared__ float wred[4];
    const int kk = (blockIdx.x - 256) * 64 + (tid >> 2), sub = tid & 3;
    const int R = kk >> 4, m = kk & 15;
    const float* base = w + (size_t)kk * C_DIM + sub * 32;
    float s = 0.f;
    #pragma unroll
    for (int q = 0; q < 4; ++q) {
      f16x8 hv;
      float4 va = *(const float4*)(base + q * 8);
      float4 vb = *(const float4*)(base + q * 8 + 4);
      float vv[8] = {va.x, va.y, va.z, va.w, vb.x, vb.y, vb.z, vb.w};
      #pragma unroll
      for (int e = 0; e < 8; ++e) { s += vv[e] * vv[e]; hv[e] = (_Float16)vv[e]; }
      *(f16x8*)(Bp + ((size_t)(R * 4 + sub) * 64 + (m + 16 * q)) * 8) = hv;
    }
    s += __shfl_xor(s, 1);                       // all 4 quad lanes: norm(kk)
    s += __shfl_xor(s, 2);
    if (sub == 0) wnorm[kk] = s;
    float wx = s;                                // block max of 64 norms
    #pragma unroll
    for (int st = 1; st <= 32; st <<= 1) wx = fmaxf(wx, __shfl_xor(wx, st));
    if ((tid & 63) == 0) wred[tid >> 6] = wx;
    __syncthreads();
    if (tid == 0)
      wnmax128[blockIdx.x - 256] =
          fmaxf(fmaxf(wred[0], wred[1]), fmaxf(wred[2], wred[3]));
  }
}

// ---------------- main GEMM + per-(row,64col-half) top-2 -------------------
// Grid (8 colsplits, 128 rowblocks), 512 thr = 8 waves.  Wave: 16 rows x
// 64 codes per half-group (4 tiles, 16 KB staged dbuf).  mfma(a=codes,
// b=rows): D col = lane&15 = x-row, D row = 4q+r = code.  6-bit in-half
// idx (t@[5:4], q@[3:2], r@[1:0]) embedded in the low mantissa of BOTH
// d1 and d2 (rides min/max); per-half emit: pd1h f32, pd2h bf16 rounded
// DOWN (conservative).  code = h*64 + (bits&63).
__global__ __launch_bounds__(512) void gemm_argmin(
    const _Float16* __restrict__ Ap, const _Float16* __restrict__ Bp,
    const float* __restrict__ wnorm,
    float* __restrict__ pd1h, unsigned short* __restrict__ pd2h,
    unsigned* __restrict__ icount, unsigned* __restrict__ hcount)
{
  __shared__ _Float16 sbuf[2][8192];             // 2 x 16 KB half-group bufs
  const int tid = threadIdx.x;
  const int lane = tid & 63, wave = tid >> 6;    // 8 waves
  const int m = lane & 15, q = lane >> 4;
  const int cs = blockIdx.x;                     // col slice (1024 codes)
  const int row0 = blockIdx.y * 128;
  const int Tr = blockIdx.y * 8 + wave;          // wave's 16-row tile

  if (cs == 0 && blockIdx.y == 0 && tid == 0) {  // ctrl zero (pre-classify)
    *icount = 0u; *hcount = 0u;
  }

#define STAGE(b, hgn) do {                                                   \
    const size_t bh_ = ((size_t)((cs * 64 + (hgn) * 4) * 4) << 9);           \
    _Pragma("unroll")                                                        \
    for (int r_ = 0; r_ < 2; ++r_) {                                         \
      __builtin_amdgcn_global_load_lds(                                      \
          (const __attribute__((address_space(1))) void*)                    \
              (Bp + bh_ + ((size_t)(r_ * 512 + tid) << 3)),                  \
          (__attribute__((address_space(3))) void*)                          \
              (&sbuf[b][(r_ * 512 + tid) << 3]),                             \
          16, 0, 0);                                                         \
    }                                                                        \
  } while (0)

  f16x8 bx[4];                                   // x-row fragments (invariant)
  #pragma unroll
  for (int kc = 0; kc < 4; ++kc)
    bx[kc] = *(const f16x8*)(Ap + (((size_t)Tr * 4 + kc) << 9) + (lane << 3));
  const int row = row0 + wave * 16 + m;
  const unsigned q2 = (unsigned)(q << 2);

  STAGE(0, 0);                                   // prologue stage

  for (int hg = 0; hg < 16; ++hg) {              // ascending half-groups
    __syncthreads();                             // buf[hg&1] ready
    if (hg < 15) STAGE((hg + 1) & 1, hg + 1);    // prefetch next half
    const _Float16* fb = &sbuf[hg & 1][0];
    f32x4 acc[4];
    #pragma unroll
    for (int t = 0; t < 4; ++t) acc[t] = (f32x4){0.f, 0.f, 0.f, 0.f};
    #pragma unroll
    for (int kc = 0; kc < 4; ++kc) {
      #pragma unroll
      for (int t = 0; t < 4; ++t) {
        f16x8 a = *(const f16x8*)(fb + ((t * 4 + kc) << 9) + (lane << 3));
        acc[t] = __builtin_amdgcn_mfma_f32_16x16x32_f16(a, bx[kc], acc[t], 0, 0, 0);
      }
    }
    // per-tile top-2 of 4 via min/max; 6-bit idx embedded pre-network
    float m1t[4], m2t[4];
    #pragma unroll
    for (int t = 0; t < 4; ++t) {
      const int cb = (cs * 64 + hg * 4 + t) * 16 + 4 * q;
      float4 wnq = *(const float4*)(wnorm + cb);
      const unsigned e0 = (unsigned)(t << 4);
      unsigned b0 = (__float_as_uint(fmaf(-2.0f, acc[t][0], wnq.x)) & 0xFFFFFFC0u) | e0;
      unsigned b1 = (__float_as_uint(fmaf(-2.0f, acc[t][1], wnq.y)) & 0xFFFFFFC0u) | (e0 | 1u);
      unsigned b2 = (__float_as_uint(fmaf(-2.0f, acc[t][2], wnq.z)) & 0xFFFFFFC0u) | (e0 | 2u);
      unsigned b3 = (__float_as_uint(fmaf(-2.0f, acc[t][3], wnq.w)) & 0xFFFFFFC0u) | (e0 | 3u);
      float v0 = __uint_as_float(b0);
      float v1 = __uint_as_float(b1);
      float v2 = __uint_as_float(b2);
      float v3 = __uint_as_float(b3);
      float l1 = fminf(v0, v1), h1 = fmaxf(v0, v1);
      float l2 = fminf(v2, v3), h2 = fmaxf(v2, v3);
      m1t[t] = fminf(l1, l2);
      m2t[t] = fminf(fminf(h1, h2), fmaxf(l1, l2));
    }
    // tournament 4 -> 1 (idx bits ride along)
    m2t[0] = fminf(fminf(m2t[0], m2t[1]), fmaxf(m1t[0], m1t[1]));
    m1t[0] = fminf(m1t[0], m1t[1]);
    m2t[2] = fminf(fminf(m2t[2], m2t[3]), fmaxf(m1t[2], m1t[3]));
    m1t[2] = fminf(m1t[2], m1t[3]);
    m2t[0] = fminf(fminf(m2t[0], m2t[2]), fmaxf(m1t[0], m1t[2]));
    m1t[0] = fminf(m1t[0], m1t[2]);
    float d1 = __uint_as_float(__float_as_uint(m1t[0]) | q2);
    float d2 = __uint_as_float(__float_as_uint(m2t[0]) | q2);
    // reduce across q (lanes differing in bits 4,5)
    #pragma unroll
    for (int s = 16; s <= 32; s <<= 1) {
      float o1 = __shfl_xor(d1, s), o2 = __shfl_xor(d2, s);
      d2 = fminf(fminf(d2, o2), fmaxf(d1, o1));
      d1 = fminf(d1, o1);
    }
    if (q == 0) {
      const int h = cs * 16 + hg;                // half index [0,128)
      pd1h[(size_t)h * N_ROWS + row] = d1;       // raw, idx-embedded
      unsigned bb = __float_as_uint(d2);
      bb += ((unsigned)((int)bb >> 31)) & 0xFFFFu;  // round toward -inf
      pd2h[(size_t)h * N_ROWS + row] = (unsigned short)(bb >> 16);
    }
  }
#undef STAGE
}

// ---------------- classify: threshold-collect over 128 halves --------------
// 4 lanes/row x 32 halves.  half pd2<=T -> (row,half) rescan item; else
// pd1<=T -> candidate h*64+(bits&63).  Cap overflows degrade to rescans
// (exactness preserved).  wm = exact max||w||^2.  Inits keys/cnt.
__global__ __launch_bounds__(256) void classify(
    const float* __restrict__ pd1h, const unsigned short* __restrict__ pd2h,
    const float* __restrict__ xnorm, const float* __restrict__ wnmax128,
    int* __restrict__ ids, unsigned* __restrict__ items,
    unsigned* __restrict__ icount, unsigned* __restrict__ hlist,
    unsigned* __restrict__ hcount, unsigned long long* __restrict__ keys,
    unsigned* __restrict__ cnt)
{
  __shared__ float wred[4];
  const int tid = threadIdx.x;
  const int gidx = blockIdx.x * 256 + tid;
  const int row = gidx >> 2, p = gidx & 3;       // 4 lanes per row (same wave)
  if (p == 0) keys[row] = ~0ull;                 // init for refine/resolve
  if (gidx < K_CODES) cnt[gidx] = 0u;
  // exact wm: block-reduce the 128 per-prep-block maxima
  float wv = wnmax128[tid & 127];
  #pragma unroll
  for (int st = 1; st <= 32; st <<= 1) wv = fmaxf(wv, __shfl_xor(wv, st));
  if ((tid & 63) == 0) wred[tid >> 6] = wv;
  __syncthreads();
  const float wm = fmaxf(fmaxf(wred[0], wred[1]), fmaxf(wred[2], wred[3]));

  float v1[32];
  float lmin = __builtin_inff();
  #pragma unroll
  for (int j = 0; j < 32; ++j) {                 // this lane's 32 half-top1s
    v1[j] = pd1h[(size_t)(p * 32 + j) * N_ROWS + row];
    lmin = fminf(lmin, v1[j]);
  }
  lmin = fminf(lmin, __shfl_xor(lmin, 1));       // global d1 across 4 lanes
  lmin = fminf(lmin, __shfl_xor(lmin, 2));
  // eps 5e-4 covers 63ulp idx-mask + conservative bf16 handling
  float twoE = 2.0f * (0.0029297f * sqrtf(xnorm[row] * wm) + 5e-4f);
  float T = lmin + twoE;
  int nc = 0, hr = 0;
  unsigned cands[6];
  #pragma unroll 8
  for (int j = 0; j < 32; ++j) {
    const int h = p * 32 + j;
    float p2 = __uint_as_float(
        (unsigned)pd2h[(size_t)h * N_ROWS + row] << 16);  // <= true pd2
    if (p2 <= T) {                               // 64-code rescan item
      unsigned hi = atomicAdd(hcount, 1u);
      hlist[hi] = ((unsigned)row << 7) | (unsigned)h;
      hr++;
    } else if (v1[j] <= T) {
      if (nc < 6) {
        cands[nc++] = (unsigned)h * 64u + (__float_as_uint(v1[j]) & 63u);
      } else {                                   // cap: degrade to rescan
        unsigned hi = atomicAdd(hcount, 1u);
        hlist[hi] = ((unsigned)row << 7) | (unsigned)h;
        hr++;
      }
    }
  }
  int nct = nc + __shfl_xor(nc, 1); nct += __shfl_xor(nct, 2);
  int hrt = hr + __shfl_xor(hr, 1); hrt += __shfl_xor(hrt, 2);
  if (hrt == 0 && nct == 1) {                    // unique candidate -> exact
    if (nc == 1) ids[row] = (int)cands[0];
  } else if (nc > 0) {                           // push this lane's cands
    unsigned base = atomicAdd(icount, (unsigned)nc);
    if (base + (unsigned)nc <= ITEMS_CAP) {
      for (int i2 = 0; i2 < nc; ++i2)
        items[base + i2] = ((unsigned)row << 13) | cands[i2];
    } else {                                     // overflow: rescan halves
      for (int i2 = 0; i2 < nc; ++i2) {
        unsigned hi = atomicAdd(hcount, 1u);
        hlist[hi] = ((unsigned)row << 7) | (cands[i2] >> 6);
      }
    }
  }
}

// ---------------- fused exact refine: items (phase A) + halves (phase B) ---
// Also zeroes sums[] (aliases pd2h region — classify was its last reader;
// resolve_scatter consumes the zeros next kernel).  x from xT + xnorm.
__global__ __launch_bounds__(256) void refine(
    const float* __restrict__ xT, const float* __restrict__ w,
    const float* __restrict__ xnorm, const float* __restrict__ wnorm,
    const unsigned* __restrict__ items, const unsigned* __restrict__ icount,
    const unsigned* __restrict__ hlist, const unsigned* __restrict__ hcount,
    unsigned long long* __restrict__ keys, float* __restrict__ sums) {
  const int tid = threadIdx.x;
  const int lane = tid & 63, wave = tid >> 6;
  // ---- zero sums: 2048 blocks x 256 thr x 2 floats = 1M floats (4 MB)
  *(float2*)(sums + ((size_t)(blockIdx.x * 256 + tid) << 1)) =
      (float2){0.f, 0.f};
  // ---- phase A: candidate items
  const unsigned ic = *icount;
  const unsigned ica = ic <= ITEMS_CAP ? ic : ITEMS_CAP;
  for (unsigned i = blockIdx.x * 256 + tid; i < ica; i += gridDim.x * 256) {
    unsigned it = items[i];
    int row = (int)(it >> 13), c = (int)(it & 8191u);
    const float* xb = xT + (size_t)row * C_DIM;
    const float* wk = w + (size_t)c * C_DIM;
    float s = 0.f;
    #pragma unroll 8
    for (int c4 = 0; c4 < 32; ++c4) {
      float4 xv = *(const float4*)(xb + c4 * 4);
      float4 wv = *(const float4*)(wk + c4 * 4);
      s = fmaf(xv.x, wv.x, s);
      s = fmaf(xv.y, wv.y, s);
      s = fmaf(xv.z, wv.z, s);
      s = fmaf(xv.w, wv.w, s);
    }
    float d = (xnorm[row] + wnorm[c]) - 2.0f * s;
    unsigned sb = __float_as_uint(d);
    sb = (sb >> 31) ? ~sb : (sb | 0x80000000u);  // sortable float bits
    unsigned long long key = ((unsigned long long)sb << 32) | (unsigned)c;
    atomicMin(&keys[row], key);                  // tie -> lowest code
  }
  // ---- phase B: 64-code half rescans
  __shared__ __align__(16) float xs[128];
  __shared__ unsigned long long red[4];
  const unsigned hc = *hcount;
  for (unsigned item = blockIdx.x; item < hc; item += gridDim.x) {
    const unsigned e = hlist[item];
    const int row = (int)(e >> 7), h = (int)(e & 127u);
    if (tid < 128)                               // stage x row (coalesced)
      xs[tid] = xT[(size_t)row * C_DIM + tid];
    __syncthreads();
    const int code = h * 64 + (tid >> 2);
    const int qt = tid & 3;
    const float* wk = w + (size_t)code * C_DIM + qt * 32;
    float s = 0.f;
    #pragma unroll
    for (int c4 = 0; c4 < 8; ++c4) {
      float4 wv = *(const float4*)(wk + c4 * 4);
      float4 xv = *(const float4*)(&xs[qt * 32 + c4 * 4]);
      s = fmaf(xv.x, wv.x, s);
      s = fmaf(xv.y, wv.y, s);
      s = fmaf(xv.z, wv.z, s);
      s = fmaf(xv.w, wv.w, s);
    }
    s += __shfl_xor(s, 1);                       // combine 4 dim-quarters
    s += __shfl_xor(s, 2);
    unsigned long long best = ~0ull;
    if (qt == 0) {
      float d = (xnorm[row] + wnorm[code]) - 2.0f * s;
      unsigned sb = __float_as_uint(d);
      sb = (sb >> 31) ? ~sb : (sb | 0x80000000u);
      best = ((unsigned long long)sb << 32) | (unsigned)code;
    }
    #pragma unroll
    for (int st = 1; st <= 32; st <<= 1) {       // 64-lane u64 butterfly
      unsigned long long ok = __shfl_xor(best, st);
      best = ok < best ? ok : best;
    }
    if (lane == 0) red[wave] = best;
    __syncthreads();
    if (tid == 0) {
      unsigned long long bk = red[0];
      #pragma unroll
      for (int wv = 1; wv < 4; ++wv) bk = red[wv] < bk ? red[wv] : bk;
      atomicMin(&keys[row], bk);
    }
    __syncthreads();                             // xs/red reused next item
  }
}

// ---------------- resolve ids + counts + out_ids + EMA scatter-add ---------
// 4 lanes per row (same wave -> lockstep: keys/ids reads precede the p==0
// ids write).  Each lane scatter-adds its 32-float quarter of xT[row] into
// sums[id] (fire-and-forget f32 atomics; order-noise ~1e-9 << tol).
__global__ __launch_bounds__(256) void resolve_scatter(
    const unsigned long long* __restrict__ keys,
    int* __restrict__ ids, unsigned* __restrict__ cnt,
    float* __restrict__ out_ids, const float* __restrict__ xT,
    float* __restrict__ sums) {
  const int gidx = blockIdx.x * 256 + threadIdx.x;   // 65536 threads
  const int row = gidx >> 2, p = gidx & 3;
  unsigned long long k = keys[row];
  int id = (k != ~0ull) ? (int)(unsigned)(k & 0xffffffffu) : ids[row];
  if (p == 0) {
    ids[row] = id;
    out_ids[row] = (float)id;
    atomicAdd(&cnt[id], 1u);
  }
  const float* xr = xT + (size_t)row * C_DIM + p * 32;
  float* sr = sums + (size_t)id * C_DIM + p * 32;
  #pragma unroll
  for (int j = 0; j < 8; ++j) {
    float4 v = *(const float4*)(xr + j * 4);
    atomicAdd(&sr[j * 4 + 0], v.x);
    atomicAdd(&sr[j * 4 + 1], v.y);
    atomicAdd(&sr[j * 4 + 2], v.z);
    atomicAdd(&sr[j * 4 + 3], v.w);
  }
}

// ---------------- fused tail: q float4 (blocks<2048) + EMA stream (rest) ---
__global__ __launch_bounds__(256) void qsum_final(
    const float* __restrict__ enc, const float* __restrict__ w,
    const int* __restrict__ ids,
    const unsigned* __restrict__ cnt, const float* __restrict__ sums,
    float* __restrict__ outq, float* __restrict__ outw) {
  if (blockIdx.x < 2048) {                       // ---- straight-through q
    int e = blockIdx.x * 1024 + threadIdx.x * 4; // linear over enc [B,C,H,W]
    int c = (e >> 10) & 127;
    int b = e >> 17;
    int n = (b << 10) | (e & 1023);              // e..e+3: same b,c
    float4 x = *(const float4*)(enc + e);
    float4 o;
    o.x = x.x + (w[(size_t)ids[n + 0] * C_DIM + c] - x.x);
    o.y = x.y + (w[(size_t)ids[n + 1] * C_DIM + c] - x.y);
    o.z = x.z + (w[(size_t)ids[n + 2] * C_DIM + c] - x.z);
    o.w = x.w + (w[(size_t)ids[n + 3] * C_DIM + c] - x.w);
    *(float4*)(outq + e) = o;
  } else {                                       // ---- EMA, wave per code
    const int tid = threadIdx.x;
    const int lane = tid & 63, wave = tid >> 6;
    const int k = (int)(blockIdx.x - 2048) * 4 + wave;
    const unsigned nk = cnt[k];
    float S0 = sums[(size_t)k * C_DIM + lane];
    float S1 = sums[(size_t)k * C_DIM + lane + 64];
    const float omd = (float)(1.0 - 0.99);
    float cf = (float)nk + 1e-12f;
    outw[(size_t)k * 128 + lane]      = 0.99f * w[(size_t)k * 128 + lane]      + omd * (S0 / cf);
    outw[(size_t)k * 128 + lane + 64] = 0.99f * w[(size_t)k * 128 + lane + 64] + omd * (S1 / cf);
  }
}

// ---------------------------------------------------------------------------
extern "C" void kernel_launch(void* const* d_in, const int* in_sizes, int n_in,
                              void* d_out, int out_size, void* d_ws, size_t ws_size,
                              hipStream_t stream) {
  const float* enc = (const float*)d_in[0];      // [16,128,32,32]
  const float* w   = (const float*)d_in[1];      // [8192,128]
  float* out = (float*)d_out;
  float* out_ids = out;                          // 16384 (ids as float)
  float* out_q   = out + N_ROWS;                 // 2097152
  float* out_w   = out + N_ROWS + N_ROWS * C_DIM;// 1048576

  char* ws = (char*)d_ws;
  _Float16* Ap  = (_Float16*)(ws);                         //  0 .. 4194304
  _Float16* Bp  = (_Float16*)(ws + 4194304);               //  .. 6291456
  float* xnorm  = (float*)(ws + 6291456);                  //  .. 6356992
  float* wnorm  = (float*)(ws + 6356992);                  //  .. 6389760
  float* pd1h   = (float*)(ws + 6389760);                  // 8 MB [128][16384]
  unsigned short* pd2h = (unsigned short*)(ws + 14778368); // 4 MB bf16
  float* sums   = (float*)(ws + 14778368);                 // ALIASES pd2h:
                                                           //  classify reads
                                                           //  pd2h, refine
                                                           //  zeroes, resolve
                                                           //  scatters (order
                                                           //  is serialized)
  float* wnmax128 = (float*)(ws + 18972672);               // 512 B
  int* ids      = (int*)(ws + 18973184);                   // 64 KB
  unsigned* hlist = (unsigned*)(ws + 19038720);            // 512 KB
  unsigned* items = (unsigned*)(ws + 19563008);            // 128 KB
  unsigned* icount = (unsigned*)(ws + 19694080);           // ctrl
  unsigned* hcount = (unsigned*)(ws + 19694084);
  unsigned* cnt    = (unsigned*)(ws + 19694096);           // 32 KB
  unsigned long long* keys = (unsigned long long*)(ws + 19792400); // 128 KB
  float* xT     = (float*)(ws + 20447248);                 // 8 MB .. 28835856
  (void)in_sizes; (void)n_in; (void)out_size; (void)ws_size;

  // no memset node: icount/hcount zeroed in gemm; keys+cnt init in classify;
  // wnmax128 plain-stored by prep; sums zeroed in refine

  prep<<<384, 256, 0, stream>>>(enc, w, Ap, Bp, xT, xnorm, wnorm, wnmax128);
  gemm_argmin<<<dim3(8, N_ROWS / 128), 512, 0, stream>>>(
      Ap, Bp, wnorm, pd1h, pd2h, icount, hcount);
  classify<<<N_ROWS * 4 / 256, 256, 0, stream>>>(
      pd1h, pd2h, xnorm, wnmax128, ids, items, icount, hlist, hcount,
      keys, cnt);
  refine<<<2048, 256, 0, stream>>>(xT, w, xnorm, wnorm, items, icount,
                                   hlist, hcount, keys, sums);
  resolve_scatter<<<N_ROWS * 4 / 256, 256, 0, stream>>>(
      keys, ids, cnt, out_ids, xT, sums);
  qsum_final<<<2048 + K_CODES / 4, 256, 0, stream>>>(
      enc, w, ids, cnt, sums, out_q, out_w);
}

// Round 13
// 187.129 us; speedup vs baseline: 1.6364x; 1.6364x over previous
//
#include <hip/hip_runtime.h>
#include <stdint.h>
#include <stddef.h>

// ---------------------------------------------------------------------------
// VQ-VAE quantizer, MI355X.  dist(n,k) = ||x||^2 + ||w_k||^2 - 2 x.w_k.
// f16 GEMM (KD=128), fragment-linear A/B.
// Refine: per-row threshold T = d1~ + 2E; exact compares via u64 atomicMin.
// R16: fragments staged via global_load_lds (2x16 KB dbuf).  R9/R20:
// gemm flat ~55-61 us across 4 structural variants -> VALU floor; frozen.
// R22: half-group (64-code) refine granularity; full-codebook rescan gone.
// R24 (this round): REVERT R23's atomic scatter-add.  resolve_scatter
// measured 132.8 us (2M scalar f32 atomicAdds -> 66 MB of RMW traffic,
// ~50x cost model miss; occupancy 8%, VALU 0.03%).  CSR path restored
// (resolve_ids -> scan_offsets -> fill_rowlist -> qsum rowlist gather) =
// R11's proven 187.9 us structure, byte-identical logic.
// ---------------------------------------------------------------------------

#define N_ROWS   16384      // B*H*W = 16*32*32
#define K_CODES  8192
#define C_DIM    128
#define ITEMS_CAP 32768u

typedef _Float16 f16x8 __attribute__((ext_vector_type(8)));
typedef float    f32x4 __attribute__((ext_vector_type(4)));

// ---------------- fused prep: blocks [0,256) pack x (+fp32 xT), [256,384) w
__global__ __launch_bounds__(256) void prep(const float* __restrict__ enc,
                                            const float* __restrict__ w,
                                            _Float16* __restrict__ Ap,
                                            _Float16* __restrict__ Bp,
                                            float* __restrict__ xT,
                                            float* __restrict__ xnorm,
                                            float* __restrict__ wnorm,
                                            float* __restrict__ wnmax128) {
  __shared__ float t[128][65];
  const int tid = threadIdx.x;
  if (blockIdx.x < 256) {                        // ---- x path
    const int b = blockIdx.x >> 4;
    const int hw0 = (blockIdx.x & 15) << 6;
    #pragma unroll
    for (int i = 0; i < 32; ++i) {
      int idx = i * 256 + tid;
      int c = idx >> 6, hwl = idx & 63;
      t[c][hwl] = enc[((size_t)(b * 128 + c) << 10) + hw0 + hwl];
    }
    __syncthreads();
    const int r = tid >> 2, sub = tid & 3;       // row-in-block, k-chunk
    const int n = (b << 10) + hw0 + r;
    const int R = n >> 4, m = n & 15;
    float s = 0.f;
    #pragma unroll
    for (int q = 0; q < 4; ++q) {
      f16x8 hv;
      float vv[8];
      #pragma unroll
      for (int e = 0; e < 8; ++e) {
        float v = t[sub * 32 + q * 8 + e][r];
        vv[e] = v;
        s += v * v;
        hv[e] = (_Float16)v;
      }
      *(f16x8*)(Ap + ((size_t)(R * 4 + sub) * 64 + (m + 16 * q)) * 8) = hv;
      *(float4*)(xT + (size_t)n * 128 + sub * 32 + q * 8) =
          (float4){vv[0], vv[1], vv[2], vv[3]};
      *(float4*)(xT + (size_t)n * 128 + sub * 32 + q * 8 + 4) =
          (float4){vv[4], vv[5], vv[6], vv[7]};
    }
    s += __shfl_xor(s, 1);
    s += __shfl_xor(s, 2);
    if (sub == 0) xnorm[n] = s;
  } else {                                       // ---- w path
    __shared__ float wred[4];
    const int kk = (blockIdx.x - 256) * 64 + (tid >> 2), sub = tid & 3;
    const int R = kk >> 4, m = kk & 15;
    const float* base = w + (size_t)kk * C_DIM + sub * 32;
    float s = 0.f;
    #pragma unroll
    for (int q = 0; q < 4; ++q) {
      f16x8 hv;
      float4 va = *(const float4*)(base + q * 8);
      float4 vb = *(const float4*)(base + q * 8 + 4);
      float vv[8] = {va.x, va.y, va.z, va.w, vb.x, vb.y, vb.z, vb.w};
      #pragma unroll
      for (int e = 0; e < 8; ++e) { s += vv[e] * vv[e]; hv[e] = (_Float16)vv[e]; }
      *(f16x8*)(Bp + ((size_t)(R * 4 + sub) * 64 + (m + 16 * q)) * 8) = hv;
    }
    s += __shfl_xor(s, 1);                       // all 4 quad lanes: norm(kk)
    s += __shfl_xor(s, 2);
    if (sub == 0) wnorm[kk] = s;
    float wx = s;                                // block max of 64 norms
    #pragma unroll
    for (int st = 1; st <= 32; st <<= 1) wx = fmaxf(wx, __shfl_xor(wx, st));
    if ((tid & 63) == 0) wred[tid >> 6] = wx;
    __syncthreads();
    if (tid == 0)
      wnmax128[blockIdx.x - 256] =
          fmaxf(fmaxf(wred[0], wred[1]), fmaxf(wred[2], wred[3]));
  }
}

// ---------------- main GEMM + per-(row,64col-half) top-2 -------------------
// Grid (8 colsplits, 128 rowblocks), 512 thr = 8 waves.  Wave: 16 rows x
// 64 codes per half-group (4 tiles, 16 KB staged dbuf).  mfma(a=codes,
// b=rows): D col = lane&15 = x-row, D row = 4q+r = code.  6-bit in-half
// idx (t@[5:4], q@[3:2], r@[1:0]) embedded in the low mantissa of BOTH
// d1 and d2 (rides min/max); per-half emit: pd1h f32, pd2h bf16 rounded
// DOWN (conservative).  code = h*64 + (bits&63).
__global__ __launch_bounds__(512) void gemm_argmin(
    const _Float16* __restrict__ Ap, const _Float16* __restrict__ Bp,
    const float* __restrict__ wnorm,
    float* __restrict__ pd1h, unsigned short* __restrict__ pd2h,
    unsigned* __restrict__ icount, unsigned* __restrict__ hcount)
{
  __shared__ _Float16 sbuf[2][8192];             // 2 x 16 KB half-group bufs
  const int tid = threadIdx.x;
  const int lane = tid & 63, wave = tid >> 6;    // 8 waves
  const int m = lane & 15, q = lane >> 4;
  const int cs = blockIdx.x;                     // col slice (1024 codes)
  const int row0 = blockIdx.y * 128;
  const int Tr = blockIdx.y * 8 + wave;          // wave's 16-row tile

  if (cs == 0 && blockIdx.y == 0 && tid == 0) {  // ctrl zero (pre-classify)
    *icount = 0u; *hcount = 0u;
  }

#define STAGE(b, hgn) do {                                                   \
    const size_t bh_ = ((size_t)((cs * 64 + (hgn) * 4) * 4) << 9);           \
    _Pragma("unroll")                                                        \
    for (int r_ = 0; r_ < 2; ++r_) {                                         \
      __builtin_amdgcn_global_load_lds(                                      \
          (const __attribute__((address_space(1))) void*)                    \
              (Bp + bh_ + ((size_t)(r_ * 512 + tid) << 3)),                  \
          (__attribute__((address_space(3))) void*)                          \
              (&sbuf[b][(r_ * 512 + tid) << 3]),                             \
          16, 0, 0);                                                         \
    }                                                                        \
  } while (0)

  f16x8 bx[4];                                   // x-row fragments (invariant)
  #pragma unroll
  for (int kc = 0; kc < 4; ++kc)
    bx[kc] = *(const f16x8*)(Ap + (((size_t)Tr * 4 + kc) << 9) + (lane << 3));
  const int row = row0 + wave * 16 + m;
  const unsigned q2 = (unsigned)(q << 2);

  STAGE(0, 0);                                   // prologue stage

  for (int hg = 0; hg < 16; ++hg) {              // ascending half-groups
    __syncthreads();                             // buf[hg&1] ready
    if (hg < 15) STAGE((hg + 1) & 1, hg + 1);    // prefetch next half
    const _Float16* fb = &sbuf[hg & 1][0];
    f32x4 acc[4];
    #pragma unroll
    for (int t = 0; t < 4; ++t) acc[t] = (f32x4){0.f, 0.f, 0.f, 0.f};
    #pragma unroll
    for (int kc = 0; kc < 4; ++kc) {
      #pragma unroll
      for (int t = 0; t < 4; ++t) {
        f16x8 a = *(const f16x8*)(fb + ((t * 4 + kc) << 9) + (lane << 3));
        acc[t] = __builtin_amdgcn_mfma_f32_16x16x32_f16(a, bx[kc], acc[t], 0, 0, 0);
      }
    }
    // per-tile top-2 of 4 via min/max; 6-bit idx embedded pre-network
    float m1t[4], m2t[4];
    #pragma unroll
    for (int t = 0; t < 4; ++t) {
      const int cb = (cs * 64 + hg * 4 + t) * 16 + 4 * q;
      float4 wnq = *(const float4*)(wnorm + cb);
      const unsigned e0 = (unsigned)(t << 4);
      unsigned b0 = (__float_as_uint(fmaf(-2.0f, acc[t][0], wnq.x)) & 0xFFFFFFC0u) | e0;
      unsigned b1 = (__float_as_uint(fmaf(-2.0f, acc[t][1], wnq.y)) & 0xFFFFFFC0u) | (e0 | 1u);
      unsigned b2 = (__float_as_uint(fmaf(-2.0f, acc[t][2], wnq.z)) & 0xFFFFFFC0u) | (e0 | 2u);
      unsigned b3 = (__float_as_uint(fmaf(-2.0f, acc[t][3], wnq.w)) & 0xFFFFFFC0u) | (e0 | 3u);
      float v0 = __uint_as_float(b0);
      float v1 = __uint_as_float(b1);
      float v2 = __uint_as_float(b2);
      float v3 = __uint_as_float(b3);
      float l1 = fminf(v0, v1), h1 = fmaxf(v0, v1);
      float l2 = fminf(v2, v3), h2 = fmaxf(v2, v3);
      m1t[t] = fminf(l1, l2);
      m2t[t] = fminf(fminf(h1, h2), fmaxf(l1, l2));
    }
    // tournament 4 -> 1 (idx bits ride along)
    m2t[0] = fminf(fminf(m2t[0], m2t[1]), fmaxf(m1t[0], m1t[1]));
    m1t[0] = fminf(m1t[0], m1t[1]);
    m2t[2] = fminf(fminf(m2t[2], m2t[3]), fmaxf(m1t[2], m1t[3]));
    m1t[2] = fminf(m1t[2], m1t[3]);
    m2t[0] = fminf(fminf(m2t[0], m2t[2]), fmaxf(m1t[0], m1t[2]));
    m1t[0] = fminf(m1t[0], m1t[2]);
    float d1 = __uint_as_float(__float_as_uint(m1t[0]) | q2);
    float d2 = __uint_as_float(__float_as_uint(m2t[0]) | q2);
    // reduce across q (lanes differing in bits 4,5)
    #pragma unroll
    for (int s = 16; s <= 32; s <<= 1) {
      float o1 = __shfl_xor(d1, s), o2 = __shfl_xor(d2, s);
      d2 = fminf(fminf(d2, o2), fmaxf(d1, o1));
      d1 = fminf(d1, o1);
    }
    if (q == 0) {
      const int h = cs * 16 + hg;                // half index [0,128)
      pd1h[(size_t)h * N_ROWS + row] = d1;       // raw, idx-embedded
      unsigned bb = __float_as_uint(d2);
      bb += ((unsigned)((int)bb >> 31)) & 0xFFFFu;  // round toward -inf
      pd2h[(size_t)h * N_ROWS + row] = (unsigned short)(bb >> 16);
    }
  }
#undef STAGE
}

// ---------------- classify: threshold-collect over 128 halves --------------
// 4 lanes/row x 32 halves.  half pd2<=T -> (row,half) rescan item; else
// pd1<=T -> candidate h*64+(bits&63).  Cap overflows degrade to rescans
// (exactness preserved).  wm = exact max||w||^2.  Inits keys/cnt.
__global__ __launch_bounds__(256) void classify(
    const float* __restrict__ pd1h, const unsigned short* __restrict__ pd2h,
    const float* __restrict__ xnorm, const float* __restrict__ wnmax128,
    int* __restrict__ ids, unsigned* __restrict__ items,
    unsigned* __restrict__ icount, unsigned* __restrict__ hlist,
    unsigned* __restrict__ hcount, unsigned long long* __restrict__ keys,
    unsigned* __restrict__ cnt)
{
  __shared__ float wred[4];
  const int tid = threadIdx.x;
  const int gidx = blockIdx.x * 256 + tid;
  const int row = gidx >> 2, p = gidx & 3;       // 4 lanes per row (same wave)
  if (p == 0) keys[row] = ~0ull;                 // init for refine/resolve
  if (gidx < K_CODES) cnt[gidx] = 0u;
  // exact wm: block-reduce the 128 per-prep-block maxima
  float wv = wnmax128[tid & 127];
  #pragma unroll
  for (int st = 1; st <= 32; st <<= 1) wv = fmaxf(wv, __shfl_xor(wv, st));
  if ((tid & 63) == 0) wred[tid >> 6] = wv;
  __syncthreads();
  const float wm = fmaxf(fmaxf(wred[0], wred[1]), fmaxf(wred[2], wred[3]));

  float v1[32];
  float lmin = __builtin_inff();
  #pragma unroll
  for (int j = 0; j < 32; ++j) {                 // this lane's 32 half-top1s
    v1[j] = pd1h[(size_t)(p * 32 + j) * N_ROWS + row];
    lmin = fminf(lmin, v1[j]);
  }
  lmin = fminf(lmin, __shfl_xor(lmin, 1));       // global d1 across 4 lanes
  lmin = fminf(lmin, __shfl_xor(lmin, 2));
  // eps 5e-4 covers 63ulp idx-mask + conservative bf16 handling
  float twoE = 2.0f * (0.0029297f * sqrtf(xnorm[row] * wm) + 5e-4f);
  float T = lmin + twoE;
  int nc = 0, hr = 0;
  unsigned cands[6];
  #pragma unroll 8
  for (int j = 0; j < 32; ++j) {
    const int h = p * 32 + j;
    float p2 = __uint_as_float(
        (unsigned)pd2h[(size_t)h * N_ROWS + row] << 16);  // <= true pd2
    if (p2 <= T) {                               // 64-code rescan item
      unsigned hi = atomicAdd(hcount, 1u);
      hlist[hi] = ((unsigned)row << 7) | (unsigned)h;
      hr++;
    } else if (v1[j] <= T) {
      if (nc < 6) {
        cands[nc++] = (unsigned)h * 64u + (__float_as_uint(v1[j]) & 63u);
      } else {                                   // cap: degrade to rescan
        unsigned hi = atomicAdd(hcount, 1u);
        hlist[hi] = ((unsigned)row << 7) | (unsigned)h;
        hr++;
      }
    }
  }
  int nct = nc + __shfl_xor(nc, 1); nct += __shfl_xor(nct, 2);
  int hrt = hr + __shfl_xor(hr, 1); hrt += __shfl_xor(hrt, 2);
  if (hrt == 0 && nct == 1) {                    // unique candidate -> exact
    if (nc == 1) ids[row] = (int)cands[0];
  } else if (nc > 0) {                           // push this lane's cands
    unsigned base = atomicAdd(icount, (unsigned)nc);
    if (base + (unsigned)nc <= ITEMS_CAP) {
      for (int i2 = 0; i2 < nc; ++i2)
        items[base + i2] = ((unsigned)row << 13) | cands[i2];
    } else {                                     // overflow: rescan halves
      for (int i2 = 0; i2 < nc; ++i2) {
        unsigned hi = atomicAdd(hcount, 1u);
        hlist[hi] = ((unsigned)row << 7) | (cands[i2] >> 6);
      }
    }
  }
}

// ---------------- fused exact refine: items (phase A) + halves (phase B) ---
// x from xT (row-contiguous fp32) + xnorm; xn is per-row additive constant.
// Phase B: one block per (row,half): 64 codes x 4 dim-quarters, coalesced
// w reads; shfl-combine quarters; wave u64-min -> atomicMin.
__global__ __launch_bounds__(256) void refine(
    const float* __restrict__ xT, const float* __restrict__ w,
    const float* __restrict__ xnorm, const float* __restrict__ wnorm,
    const unsigned* __restrict__ items, const unsigned* __restrict__ icount,
    const unsigned* __restrict__ hlist, const unsigned* __restrict__ hcount,
    unsigned long long* __restrict__ keys) {
  const int tid = threadIdx.x;
  const int lane = tid & 63, wave = tid >> 6;
  // ---- phase A: candidate items
  const unsigned ic = *icount;
  const unsigned ica = ic <= ITEMS_CAP ? ic : ITEMS_CAP;
  for (unsigned i = blockIdx.x * 256 + tid; i < ica; i += gridDim.x * 256) {
    unsigned it = items[i];
    int row = (int)(it >> 13), c = (int)(it & 8191u);
    const float* xb = xT + (size_t)row * C_DIM;
    const float* wk = w + (size_t)c * C_DIM;
    float s = 0.f;
    #pragma unroll 8
    for (int c4 = 0; c4 < 32; ++c4) {
      float4 xv = *(const float4*)(xb + c4 * 4);
      float4 wv = *(const float4*)(wk + c4 * 4);
      s = fmaf(xv.x, wv.x, s);
      s = fmaf(xv.y, wv.y, s);
      s = fmaf(xv.z, wv.z, s);
      s = fmaf(xv.w, wv.w, s);
    }
    float d = (xnorm[row] + wnorm[c]) - 2.0f * s;
    unsigned sb = __float_as_uint(d);
    sb = (sb >> 31) ? ~sb : (sb | 0x80000000u);  // sortable float bits
    unsigned long long key = ((unsigned long long)sb << 32) | (unsigned)c;
    atomicMin(&keys[row], key);                  // tie -> lowest code
  }
  // ---- phase B: 64-code half rescans
  __shared__ __align__(16) float xs[128];
  __shared__ unsigned long long red[4];
  const unsigned hc = *hcount;
  for (unsigned item = blockIdx.x; item < hc; item += gridDim.x) {
    const unsigned e = hlist[item];
    const int row = (int)(e >> 7), h = (int)(e & 127u);
    if (tid < 128)                               // stage x row (coalesced)
      xs[tid] = xT[(size_t)row * C_DIM + tid];
    __syncthreads();
    const int code = h * 64 + (tid >> 2);
    const int qt = tid & 3;
    const float* wk = w + (size_t)code * C_DIM + qt * 32;
    float s = 0.f;
    #pragma unroll
    for (int c4 = 0; c4 < 8; ++c4) {
      float4 wv = *(const float4*)(wk + c4 * 4);
      float4 xv = *(const float4*)(&xs[qt * 32 + c4 * 4]);
      s = fmaf(xv.x, wv.x, s);
      s = fmaf(xv.y, wv.y, s);
      s = fmaf(xv.z, wv.z, s);
      s = fmaf(xv.w, wv.w, s);
    }
    s += __shfl_xor(s, 1);                       // combine 4 dim-quarters
    s += __shfl_xor(s, 2);
    unsigned long long best = ~0ull;
    if (qt == 0) {
      float d = (xnorm[row] + wnorm[code]) - 2.0f * s;
      unsigned sb = __float_as_uint(d);
      sb = (sb >> 31) ? ~sb : (sb | 0x80000000u);
      best = ((unsigned long long)sb << 32) | (unsigned)code;
    }
    #pragma unroll
    for (int st = 1; st <= 32; st <<= 1) {       // 64-lane u64 butterfly
      unsigned long long ok = __shfl_xor(best, st);
      best = ok < best ? ok : best;
    }
    if (lane == 0) red[wave] = best;
    __syncthreads();
    if (tid == 0) {
      unsigned long long bk = red[0];
      #pragma unroll
      for (int wv = 1; wv < 4; ++wv) bk = red[wv] < bk ? red[wv] : bk;
      atomicMin(&keys[row], bk);
    }
    __syncthreads();                             // xs/red reused next item
  }
}

// ---------------- resolve final ids + int counts + out_ids -----------------
__global__ void resolve_ids(const unsigned long long* __restrict__ keys,
                            int* __restrict__ ids, unsigned* __restrict__ cnt,
                            float* __restrict__ out_ids) {
  int row = blockIdx.x * 256 + threadIdx.x;
  unsigned long long k = keys[row];
  int id = (k != ~0ull) ? (int)(unsigned)(k & 0xffffffffu) : ids[row];
  ids[row] = id;
  out_ids[row] = (float)id;
  atomicAdd(&cnt[id], 1u);
}

// ---------------- exclusive scan of counts -> offs + cursor (1 block) ------
__global__ __launch_bounds__(256) void scan_offsets(
    const unsigned* __restrict__ cnt,
    unsigned* __restrict__ offs, unsigned* __restrict__ cursor) {
  __shared__ unsigned tot[256];
  const int tid = threadIdx.x;
  unsigned local[32], run = 0;
  #pragma unroll
  for (int i = 0; i < 32; ++i) { local[i] = run; run += cnt[tid * 32 + i]; }
  tot[tid] = run;
  __syncthreads();
  for (int st = 1; st < 256; st <<= 1) {
    unsigned v = (tid >= st) ? tot[tid - st] : 0u;
    __syncthreads();
    tot[tid] += v;
    __syncthreads();
  }
  unsigned excl = (tid == 0) ? 0u : tot[tid - 1];
  #pragma unroll
  for (int i = 0; i < 32; ++i) {
    unsigned o = excl + local[i];
    offs[tid * 32 + i] = o;
    cursor[tid * 32 + i] = o;
  }
}

// ---------------- fill CSR row list (parallel, 64 blocks) ------------------
__global__ void fill_rowlist(const int* __restrict__ ids,
                             unsigned* __restrict__ cursor,
                             int* __restrict__ rowlist) {
  int row = blockIdx.x * 256 + threadIdx.x;
  unsigned slot = atomicAdd(&cursor[ids[row]], 1u);
  rowlist[slot] = row;
}

// ---------------- fused tail: q float4 (blocks<2048) + EMA gather (rest) ---
__global__ __launch_bounds__(256) void qsum_final(
    const float* __restrict__ enc, const float* __restrict__ w,
    const int* __restrict__ ids,
    const unsigned* __restrict__ cnt, const unsigned* __restrict__ offs,
    const int* __restrict__ rowlist, const float* __restrict__ xT,
    float* __restrict__ outq, float* __restrict__ outw) {
  if (blockIdx.x < 2048) {                       // ---- straight-through q
    int e = blockIdx.x * 1024 + threadIdx.x * 4; // linear over enc [B,C,H,W]
    int c = (e >> 10) & 127;
    int b = e >> 17;
    int n = (b << 10) | (e & 1023);              // e..e+3: same b,c
    float4 x = *(const float4*)(enc + e);
    float4 o;
    o.x = x.x + (w[(size_t)ids[n + 0] * C_DIM + c] - x.x);
    o.y = x.y + (w[(size_t)ids[n + 1] * C_DIM + c] - x.y);
    o.z = x.z + (w[(size_t)ids[n + 2] * C_DIM + c] - x.z);
    o.w = x.w + (w[(size_t)ids[n + 3] * C_DIM + c] - x.w);
    *(float4*)(outq + e) = o;
  } else {                                       // ---- EMA gather, wave/code
    const int tid = threadIdx.x;
    const int lane = tid & 63, wave = tid >> 6;
    const int k = (int)(blockIdx.x - 2048) * 4 + wave;
    const unsigned n0 = offs[k], nk = cnt[k];
    float S0a = 0.f, S0b = 0.f, S0c = 0.f, S0d = 0.f;
    float S1a = 0.f, S1b = 0.f, S1c = 0.f, S1d = 0.f;
    unsigned i = 0;
    for (; i + 4 <= nk; i += 4) {                // 4-way ILP partial sums
      int r0 = rowlist[n0 + i],     r1 = rowlist[n0 + i + 1];
      int r2 = rowlist[n0 + i + 2], r3 = rowlist[n0 + i + 3];
      S0a += xT[(size_t)r0 * 128 + lane];      S1a += xT[(size_t)r0 * 128 + lane + 64];
      S0b += xT[(size_t)r1 * 128 + lane];      S1b += xT[(size_t)r1 * 128 + lane + 64];
      S0c += xT[(size_t)r2 * 128 + lane];      S1c += xT[(size_t)r2 * 128 + lane + 64];
      S0d += xT[(size_t)r3 * 128 + lane];      S1d += xT[(size_t)r3 * 128 + lane + 64];
    }
    for (; i < nk; ++i) {
      int r = rowlist[n0 + i];
      S0a += xT[(size_t)r * 128 + lane];
      S1a += xT[(size_t)r * 128 + lane + 64];
    }
    float S0 = (S0a + S0b) + (S0c + S0d);
    float S1 = (S1a + S1b) + (S1c + S1d);
    const float omd = (float)(1.0 - 0.99);
    float cf = (float)nk + 1e-12f;
    outw[(size_t)k * 128 + lane]      = 0.99f * w[(size_t)k * 128 + lane]      + omd * (S0 / cf);
    outw[(size_t)k * 128 + lane + 64] = 0.99f * w[(size_t)k * 128 + lane + 64] + omd * (S1 / cf);
  }
}

// ---------------------------------------------------------------------------
extern "C" void kernel_launch(void* const* d_in, const int* in_sizes, int n_in,
                              void* d_out, int out_size, void* d_ws, size_t ws_size,
                              hipStream_t stream) {
  const float* enc = (const float*)d_in[0];      // [16,128,32,32]
  const float* w   = (const float*)d_in[1];      // [8192,128]
  float* out = (float*)d_out;
  float* out_ids = out;                          // 16384 (ids as float)
  float* out_q   = out + N_ROWS;                 // 2097152
  float* out_w   = out + N_ROWS + N_ROWS * C_DIM;// 1048576

  char* ws = (char*)d_ws;
  _Float16* Ap  = (_Float16*)(ws);                         //  0 .. 4194304
  _Float16* Bp  = (_Float16*)(ws + 4194304);               //  .. 6291456
  float* xnorm  = (float*)(ws + 6291456);                  //  .. 6356992
  float* wnorm  = (float*)(ws + 6356992);                  //  .. 6389760
  float* pd1h   = (float*)(ws + 6389760);                  // 8 MB [128][16384]
  unsigned short* pd2h = (unsigned short*)(ws + 14778368); // 4 MB bf16
  float* wnmax128 = (float*)(ws + 18972672);               // 512 B
  int* ids      = (int*)(ws + 18973184);                   // 64 KB
  unsigned* hlist = (unsigned*)(ws + 19038720);            // 512 KB
  unsigned* items = (unsigned*)(ws + 19563008);            // 128 KB
  unsigned* icount = (unsigned*)(ws + 19694080);           // ctrl
  unsigned* hcount = (unsigned*)(ws + 19694084);
  unsigned* cnt    = (unsigned*)(ws + 19694096);           // 32 KB
  unsigned* offs   = (unsigned*)(ws + 19726864);           // 32 KB
  unsigned* cursor = (unsigned*)(ws + 19759632);           // 32 KB
  unsigned long long* keys = (unsigned long long*)(ws + 19792400); // 128 KB
  int* rowlist  = (int*)(ws + 19923472);                   // 64 KB
  float* xT     = (float*)(ws + 20447248);                 // 8 MB .. 28835856
  (void)in_sizes; (void)n_in; (void)out_size; (void)ws_size;

  // no memset node: icount/hcount zeroed in gemm; keys+cnt init in classify;
  // wnmax128 plain-stored by prep

  prep<<<384, 256, 0, stream>>>(enc, w, Ap, Bp, xT, xnorm, wnorm, wnmax128);
  gemm_argmin<<<dim3(8, N_ROWS / 128), 512, 0, stream>>>(
      Ap, Bp, wnorm, pd1h, pd2h, icount, hcount);
  classify<<<N_ROWS * 4 / 256, 256, 0, stream>>>(
      pd1h, pd2h, xnorm, wnmax128, ids, items, icount, hlist, hcount,
      keys, cnt);
  refine<<<2048, 256, 0, stream>>>(xT, w, xnorm, wnorm, items, icount,
                                   hlist, hcount, keys);
  resolve_ids<<<N_ROWS / 256, 256, 0, stream>>>(keys, ids, cnt, out_ids);
  scan_offsets<<<1, 256, 0, stream>>>(cnt, offs, cursor);
  fill_rowlist<<<N_ROWS / 256, 256, 0, stream>>>(ids, cursor, rowlist);
  qsum_final<<<2048 + K_CODES / 4, 256, 0, stream>>>(
      enc, w, ids, cnt, offs, rowlist, xT, out_q, out_w);
}